// Round 9
// baseline (734.655 us; speedup 1.0000x reference)
//
#include <hip/hip_runtime.h>

constexpr int TPB  = 256;
constexpr int TPBW = 1024;
constexpr int P    = 256;              // edge slices
constexpr int BSH  = 8;                // 256 nodes per bucket
constexpr int MAXB = 512;              // max buckets (N <= 131072)
constexpr int HW   = 16384;            // nibble row-hist words (N <= 131072)

// ---------------------------------------------- per-slice bucket counts (cols)
__global__ void k_prep(const int* __restrict__ col, int E, int sliceLen,
                       int* __restrict__ cntTab, int NBKT) {
    __shared__ int cl[MAXB];
    const int p = blockIdx.x;
    for (int t = threadIdx.x; t < NBKT; t += TPBW) cl[t] = 0;
    __syncthreads();
    const int s = p * sliceLen, send = min(s + sliceLen, E);
    for (int e = s + threadIdx.x; e < send; e += TPBW)
        atomicAdd(&cl[col[e] >> BSH], 1);
    __syncthreads();
    for (int b = threadIdx.x; b < NBKT; b += TPBW) cntTab[b * P + p] = cl[b];
}

// ---------------------------------------------- nibble row histogram (degree)
__global__ void k_histrow(const int* __restrict__ row, int E, int sliceLen,
                          unsigned int* __restrict__ partialR, int W) {
    __shared__ unsigned int lh[HW];
    const int p = blockIdx.x;
    for (int t = threadIdx.x; t < W; t += TPBW) lh[t] = 0;
    __syncthreads();
    const int s = p * sliceLen, send = min(s + sliceLen, E);
    for (int e = s + threadIdx.x; e < send; e += TPBW) {
        int v = row[e];
        atomicAdd(&lh[v >> 3], 1u << ((v & 7) * 4));
    }
    __syncthreads();
    for (int w = threadIdx.x; w < W; w += TPBW)
        partialR[(size_t)p * W + w] = lh[w];
}

// ---------------------------------------------- hierarchical scan of cntTab
__global__ void k_scanB1(int* __restrict__ tab, int total, int* __restrict__ bs) {
    __shared__ int tmp[2][1024];
    const int t = threadIdx.x, idx = blockIdx.x * 1024 + t;
    int v = (idx < total) ? tab[idx] : 0;
    int buf = 0;
    tmp[0][t] = v;
    __syncthreads();
    for (int off = 1; off < 1024; off <<= 1) {
        int nv = tmp[buf][t] + ((t >= off) ? tmp[buf][t - off] : 0);
        buf ^= 1; tmp[buf][t] = nv;
        __syncthreads();
    }
    int incl = tmp[buf][t];
    if (idx < total) tab[idx] = incl - v;
    if (t == 1023) bs[blockIdx.x] = incl;
}

__global__ void k_scan2(int* __restrict__ bsum, int NB) {
    __shared__ int tmp[2][256];
    __shared__ int carry_s;
    int t = threadIdx.x;
    if (t == 0) carry_s = 0;
    __syncthreads();
    for (int chunk = 0; chunk < NB; chunk += 256) {
        int idx = chunk + t;
        int v = (idx < NB) ? bsum[idx] : 0;
        int buf = 0;
        tmp[0][t] = v;
        __syncthreads();
        for (int off = 1; off < 256; off <<= 1) {
            int nv = tmp[buf][t] + ((t >= off) ? tmp[buf][t - off] : 0);
            buf ^= 1; tmp[buf][t] = nv;
            __syncthreads();
        }
        int incl = tmp[buf][t];
        int carry = carry_s;
        if (idx < NB) bsum[idx] = carry + incl - v;
        __syncthreads();
        if (t == 255) carry_s = carry + incl;
        __syncthreads();
    }
}

__global__ void k_scanB3(int* __restrict__ tab, int total, const int* __restrict__ bs,
                         int* __restrict__ segBase, int NBKT, int E) {
    const int idx = blockIdx.x * 1024 + threadIdx.x;
    if (idx < total) {
        int v = tab[idx] + bs[blockIdx.x];
        tab[idx] = v;
        if ((idx & (P - 1)) == 0) segBase[idx / P] = v;
    }
    if (idx == 0) segBase[NBKT] = E;
}

// ---------------------------------------------- reduce row partials -> dis
__global__ void k_disr(const unsigned int* __restrict__ partialR, int W, int N,
                       float* __restrict__ dis) {
    const int w = blockIdx.x * blockDim.x + threadIdx.x;
    if (w >= W) return;
    const unsigned int* pr = partialR + w;
    unsigned int accA = 0, accB = 0;            // byte lanes, totals <= ~66
    for (int p = 0; p < P; p++) {
        unsigned int v = pr[(size_t)p * W];
        accA += v & 0x0F0F0F0Fu;
        accB += (v >> 4) & 0x0F0F0F0Fu;
    }
    int d[8];
    d[0] = accA & 255; d[2] = (accA >> 8) & 255;
    d[4] = (accA >> 16) & 255; d[6] = accA >> 24;
    d[1] = accB & 255; d[3] = (accB >> 8) & 255;
    d[5] = (accB >> 16) & 255; d[7] = accB >> 24;
    const int n0 = w * 8;
#pragma unroll
    for (int k = 0; k < 8; k++)
        if (n0 + k < N) dis[n0 + k] = d[k] ? rsqrtf((float)d[k]) : 0.f;
}

// ------------------------------- stage into bucket-major runs (8B+8B records)
__global__ void k_stage(const int* __restrict__ ei, const float2* __restrict__ ea,
                        const float* __restrict__ dis,
                        int E, int sliceLen, const int* __restrict__ cntTab,
                        int NBKT, int2* __restrict__ sa, float2* __restrict__ sb) {
    __shared__ int lb[MAXB], lbase[MAXB];
    const int p = blockIdx.x;
    for (int t = threadIdx.x; t < NBKT; t += TPBW) {
        lb[t] = 0;
        lbase[t] = cntTab[t * P + p];
    }
    __syncthreads();
    const int* colA = ei + E;
    const int s = p * sliceLen, send = min(s + sliceLen, E);
    for (int e = s + threadIdx.x; e < send; e += TPBW) {
        int c = colA[e];
        int r = ei[e];
        int b = c >> BSH;
        float nrm = dis[r] * dis[c];
        int pos = lbase[b] + atomicAdd(&lb[b], 1);
        float2 ev = ea[e];
        sa[pos] = make_int2((r << 8) | (c & 255), __float_as_int(nrm));
        sb[pos] = make_float2(nrm * ev.x, nrm * ev.y);
    }
}

// ------------------- pass A: per-bucket layer-1 edge sums + in-counts (no rec)
__global__ void k_accA(const int2* __restrict__ sa, const float2* __restrict__ sb,
                       const int* __restrict__ segBase, const float* __restrict__ x,
                       int N, int* __restrict__ cnt, float* __restrict__ acc1) {
    __shared__ float lac[5 * 256];      // plane-major [q][j]
    __shared__ int lcnt[256];
    const int b = blockIdx.x, t = threadIdx.x;
    const int s0 = segBase[b], s1 = segBase[b + 1], c0 = b << BSH;
    if (t < 256) lcnt[t] = 0;
    for (int k = t; k < 1280; k += TPBW) lac[k] = 0.f;
    __syncthreads();
    for (int e = s0 + t; e < s1; e += TPBW) {
        int2 ra = sa[e];
        float2 rb = sb[e];
        int j = ra.x & 255;
        int r = ((unsigned)ra.x) >> 8;
        float nrm = __int_as_float(ra.y);
        const float* xr = x + 3 * (long)r;
        atomicAdd(&lcnt[j], 1);
        unsafeAtomicAdd(&lac[0 * 256 + j], nrm * xr[0]);
        unsafeAtomicAdd(&lac[1 * 256 + j], nrm * xr[1]);
        unsafeAtomicAdd(&lac[2 * 256 + j], nrm * xr[2]);
        unsafeAtomicAdd(&lac[3 * 256 + j], rb.x);
        unsafeAtomicAdd(&lac[4 * 256 + j], rb.y);
    }
    __syncthreads();
    const int nb = min(256, N - c0);
    if (t < 256 && t < nb) cnt[c0 + t] = lcnt[t];
    for (int k = t; k < 1280; k += TPBW) {
        int q = k >> 8, j = k & 255;
        if (j < nb) acc1[(size_t)q * N + c0 + j] = lac[k];
    }
}

// ---------------------------------------------- layer-1 node update (no edges)
__global__ void k_node1(const float* __restrict__ x, const float* __restrict__ acc,
                        const int* __restrict__ cnt,
                        const float* __restrict__ Wc, const float* __restrict__ bc,
                        const float* __restrict__ Wn,
                        float* __restrict__ h, int N) {
    __shared__ float sWc[3 * 16], sbc[16], sWn[5 * 16];
    for (int t = threadIdx.x; t < 48; t += blockDim.x) sWc[t] = Wc[t];
    for (int t = threadIdx.x; t < 16; t += blockDim.x) sbc[t] = bc[t];
    for (int t = threadIdx.x; t < 80; t += blockDim.x) sWn[t] = Wn[t];
    __syncthreads();
    int i = blockIdx.x * blockDim.x + threadIdx.x;
    if (i >= N) return;
    float inv = 1.0f / fmaxf((float)cnt[i], 1.0f);
    float m[5];
#pragma unroll
    for (int j = 0; j < 5; j++) m[j] = acc[(size_t)j * N + i] * inv;
    float xv[3];
#pragma unroll
    for (int j = 0; j < 3; j++) xv[j] = x[3 * (long)i + j];
    float o[16];
#pragma unroll
    for (int k = 0; k < 16; k++) {
        float v = sbc[k];
#pragma unroll
        for (int j = 0; j < 3; j++) v += xv[j] * sWc[j * 16 + k];
#pragma unroll
        for (int j = 0; j < 5; j++) v += m[j] * sWn[j * 16 + k];
        o[k] = fmaxf(v, 0.0f);
    }
    float4* hp = (float4*)(h + 16 * (long)i);
#pragma unroll
    for (int q = 0; q < 4; q++)
        hp[q] = make_float4(o[4 * q], o[4 * q + 1], o[4 * q + 2], o[4 * q + 3]);
}

// ---- pass B: per-bucket layer-2 aggregation + node update + pooling (fused)
__global__ __launch_bounds__(TPBW)
void k_g2(const int2* __restrict__ sa, const int* __restrict__ segBase,
          const float* __restrict__ h, const int* __restrict__ cnt,
          const float* __restrict__ acc1, const int* __restrict__ batch, int N,
          const float* __restrict__ Wc, const float* __restrict__ bc,
          const float* __restrict__ Wn,
          float* __restrict__ pool, int* __restrict__ poolcnt) {
    __shared__ float sm[16][256];       // bank = j&31, random j -> ~2-way (free)
    __shared__ float sWc[256], sbc[16], sWn[288];
    __shared__ float sp[1024];
    __shared__ int   sc[64];
    const int b = blockIdx.x, t = threadIdx.x;
    const int s0 = segBase[b], s1 = segBase[b + 1], c0 = b << BSH;
    for (int k = t; k < 256; k += TPBW) sWc[k] = Wc[k];
    for (int k = t; k < 16;  k += TPBW) sbc[k] = bc[k];
    for (int k = t; k < 288; k += TPBW) sWn[k] = Wn[k];
    for (int k = t; k < 4096; k += TPBW) ((float*)sm)[k] = 0.f;
    for (int k = t; k < 1024; k += TPBW) sp[k] = 0.f;
    if (t < 64) sc[t] = 0;
    __syncthreads();
    for (int e = s0 + t; e < s1; e += TPBW) {
        int2 ra = sa[e];
        int j = ra.x & 255;
        int r = ((unsigned)ra.x) >> 8;
        float nrm = __int_as_float(ra.y);
        const float4* hr = (const float4*)(h + 16 * (long)r);
        float4 h0 = hr[0], h1 = hr[1], h2 = hr[2], h3 = hr[3];
        unsafeAtomicAdd(&sm[0][j],  nrm * h0.x);
        unsafeAtomicAdd(&sm[1][j],  nrm * h0.y);
        unsafeAtomicAdd(&sm[2][j],  nrm * h0.z);
        unsafeAtomicAdd(&sm[3][j],  nrm * h0.w);
        unsafeAtomicAdd(&sm[4][j],  nrm * h1.x);
        unsafeAtomicAdd(&sm[5][j],  nrm * h1.y);
        unsafeAtomicAdd(&sm[6][j],  nrm * h1.z);
        unsafeAtomicAdd(&sm[7][j],  nrm * h1.w);
        unsafeAtomicAdd(&sm[8][j],  nrm * h2.x);
        unsafeAtomicAdd(&sm[9][j],  nrm * h2.y);
        unsafeAtomicAdd(&sm[10][j], nrm * h2.z);
        unsafeAtomicAdd(&sm[11][j], nrm * h2.w);
        unsafeAtomicAdd(&sm[12][j], nrm * h3.x);
        unsafeAtomicAdd(&sm[13][j], nrm * h3.y);
        unsafeAtomicAdd(&sm[14][j], nrm * h3.z);
        unsafeAtomicAdd(&sm[15][j], nrm * h3.w);
    }
    __syncthreads();
    if (t < 256) {
        int node = c0 + t;
        if (node < N) {
            float dg = (float)cnt[node];
            float inv = 1.0f / fmaxf(dg, 1.0f);
            float m[18];
#pragma unroll
            for (int k = 0; k < 16; k++) m[k] = sm[k][t] * inv;
            m[16] = acc1[(size_t)3 * N + node] * inv;
            m[17] = acc1[(size_t)4 * N + node] * inv;
            float hv[16];
            const float4* hp = (const float4*)(h + 16 * (long)node);
#pragma unroll
            for (int q = 0; q < 4; q++) {
                float4 t4 = hp[q];
                hv[4 * q] = t4.x; hv[4 * q + 1] = t4.y;
                hv[4 * q + 2] = t4.z; hv[4 * q + 3] = t4.w;
            }
            int g = batch[node];
            atomicAdd(&sc[g], 1);
#pragma unroll
            for (int k = 0; k < 16; k++) {
                float v = sbc[k];
#pragma unroll
                for (int j = 0; j < 16; j++) v += hv[j] * sWc[j * 16 + k];
#pragma unroll
                for (int j = 0; j < 18; j++) v += m[j] * sWn[j * 16 + k];
                v = fmaxf(v, 0.0f);
                unsafeAtomicAdd(&sp[g * 16 + k], v);
            }
        }
    }
    __syncthreads();
    for (int k = t; k < 1024; k += TPBW)
        if (sp[k] != 0.0f) unsafeAtomicAdd(&pool[k], sp[k]);
    if (t < 64 && sc[t]) atomicAdd(&poolcnt[t], sc[t]);
}

// ---------------------------------------------------------------- MLP head
__global__ void k_final(const float* __restrict__ pool, const int* __restrict__ poolcnt,
                        const float* __restrict__ Wl1, const float* __restrict__ bl1,
                        const float* __restrict__ Wl2, const float* __restrict__ bl2,
                        float* __restrict__ out) {
    int g = threadIdx.x;
    if (g >= 64) return;
    float inv = 1.0f / fmaxf((float)poolcnt[g], 1.0f);
    float gv[16];
#pragma unroll
    for (int k = 0; k < 16; k++) gv[k] = pool[g * 16 + k] * inv;
    float t[16];
#pragma unroll
    for (int k = 0; k < 16; k++) {
        float v = bl1[k];
#pragma unroll
        for (int j = 0; j < 16; j++) v += gv[j] * Wl1[j * 16 + k];
        t[k] = fmaxf(v, 0.0f);
    }
    float o0 = bl2[0], o1 = bl2[1];
#pragma unroll
    for (int j = 0; j < 16; j++) {
        o0 += t[j] * Wl2[j * 2 + 0];
        o1 += t[j] * Wl2[j * 2 + 1];
    }
    out[2 * g + 0] = o0;
    out[2 * g + 1] = o1;
}

extern "C" void kernel_launch(void* const* d_in, const int* in_sizes, int n_in,
                              void* d_out, int out_size, void* d_ws, size_t ws_size,
                              hipStream_t stream) {
    const float* x     = (const float*)d_in[0];
    const int*   ei    = (const int*)  d_in[1];
    const float* ea    = (const float*)d_in[2];
    const int*   batch = (const int*)  d_in[3];
    const float* Wc1   = (const float*)d_in[4];
    const float* bc1   = (const float*)d_in[5];
    const float* Wn1   = (const float*)d_in[6];
    const float* Wc2   = (const float*)d_in[7];
    const float* bc2   = (const float*)d_in[8];
    const float* Wn2   = (const float*)d_in[9];
    const float* Wl1   = (const float*)d_in[10];
    const float* bl1   = (const float*)d_in[11];
    const float* Wl2   = (const float*)d_in[12];
    const float* bl2   = (const float*)d_in[13];
    float* out = (float*)d_out;

    const int N  = in_sizes[0] / 3;
    const int E  = in_sizes[1] / 2;
    const int NBKT = (N + 255) >> BSH;
    const int W  = (N + 7) >> 3;
    const int total = NBKT * P;
    const int NSB = (total + 1023) / 1024;
    const int sliceLen = (E + P - 1) / P;
    const int N8 = (N + 7) & ~7;

    char* ws = (char*)d_ws;
    size_t o = 0;
    auto alloc = [&](size_t bytes) {
        void* p = ws + o;
        o += (bytes + 255) & ~(size_t)255;
        return p;
    };
    // zeroed region (pool + poolcnt only)
    float* pool    = (float*)alloc(64 * 16 * 4);
    int*   poolcnt = (int*)  alloc(64 * 4);
    size_t zbytes = o;
    // non-zeroed (fully overwritten before read)
    float* dis     = (float*)alloc((size_t)N8 * 4);
    int*   cnt     = (int*)  alloc((size_t)N8 * 4);
    int*   cntTab  = (int*)  alloc((size_t)total * 4);
    int*   bs      = (int*)  alloc((size_t)NSB * 4);
    int*   segBase = (int*)  alloc((size_t)(NBKT + 1) * 4);
    float* acc1    = (float*)alloc((size_t)5 * N * 4);   // plane-major [5][N]
    // region A: partialR [histrow..disr] then h [node1..g2]
    size_t szPR = (size_t)P * W * 4, szH = (size_t)N * 16 * 4;
    char* regionA = (char*)alloc(szPR > szH ? szPR : szH);
    unsigned int* partialR = (unsigned int*)regionA;
    float* h = (float*)regionA;
    int2*   sa = (int2*)  alloc((size_t)E * 8);
    float2* sb = (float2*)alloc((size_t)E * 8);
    (void)ws_size;

    hipMemsetAsync(d_ws, 0, zbytes, stream);

    const int gN = (N + TPB - 1) / TPB;
    k_prep   <<<P, TPBW, 0, stream>>>(ei + E, E, sliceLen, cntTab, NBKT);
    k_histrow<<<P, TPBW, 0, stream>>>(ei, E, sliceLen, partialR, W);
    k_scanB1 <<<NSB, 1024, 0, stream>>>(cntTab, total, bs);
    k_scan2  <<<1, 256, 0, stream>>>(bs, NSB);
    k_scanB3 <<<NSB, 1024, 0, stream>>>(cntTab, total, bs, segBase, NBKT, E);
    k_disr   <<<(W + TPB - 1) / TPB, TPB, 0, stream>>>(partialR, W, N, dis);
    k_stage  <<<P, TPBW, 0, stream>>>(ei, (const float2*)ea, dis, E, sliceLen,
                                      cntTab, NBKT, sa, sb);
    k_accA   <<<NBKT, TPBW, 0, stream>>>(sa, sb, segBase, x, N, cnt, acc1);
    k_node1  <<<gN, TPB, 0, stream>>>(x, acc1, cnt, Wc1, bc1, Wn1, h, N);
    k_g2     <<<NBKT, TPBW, 0, stream>>>(sa, segBase, h, cnt, acc1, batch, N,
                                         Wc2, bc2, Wn2, pool, poolcnt);
    k_final  <<<1, 64, 0, stream>>>(pool, poolcnt, Wl1, bl1, Wl2, bl2, out);
}

// Round 10
// 430.153 us; speedup vs baseline: 1.7079x; 1.7079x over previous
//
#include <hip/hip_runtime.h>

constexpr int TPB  = 256;
constexpr int TPBW = 1024;
constexpr int P    = 256;              // edge slices
constexpr int BSH  = 7;                // 128-node buckets
constexpr int BKN  = 128;
constexpr int MAXB = 800;              // max buckets (N <= 102400)
constexpr int HWL  = 12800;            // nibble hist words (N <= 102400)
constexpr int SBUF = 4608;             // sorted-segment LDS capacity (int2)
constexpr int ITER = 6;                // max seg edges per thread (6*1024 >= seg max)

// ---------------- fused: per-slice col bucket counts + row nibble histogram
__global__ __launch_bounds__(TPBW)
void k_prep2(const int* __restrict__ ei, int E, int sliceLen, int W, int NBKT,
             unsigned int* __restrict__ partialR, int* __restrict__ cntTab) {
    __shared__ unsigned int lh[HWL];
    __shared__ int cl[MAXB];
    const int p = blockIdx.x;
    for (int t = threadIdx.x; t < W; t += TPBW) lh[t] = 0;
    for (int t = threadIdx.x; t < NBKT; t += TPBW) cl[t] = 0;
    __syncthreads();
    const int* colA = ei + E;
    const int s = p * sliceLen, send = min(s + sliceLen, E);
    for (int e = s + threadIdx.x; e < send; e += TPBW) {
        int r = ei[e], c = colA[e];
        atomicAdd(&lh[r >> 3], 1u << ((r & 7) * 4));   // per-slice count <= ~7 < 15
        atomicAdd(&cl[c >> BSH], 1);
    }
    __syncthreads();
    for (int w = threadIdx.x; w < W; w += TPBW) partialR[(size_t)p * W + w] = lh[w];
    for (int b = threadIdx.x; b < NBKT; b += TPBW) cntTab[b * P + p] = cl[b];
}

// ---------------------------------------------- hierarchical scan of cntTab
__global__ void k_scanB1(int* __restrict__ tab, int total, int* __restrict__ bs) {
    __shared__ int tmp[2][1024];
    const int t = threadIdx.x, idx = blockIdx.x * 1024 + t;
    int v = (idx < total) ? tab[idx] : 0;
    int buf = 0;
    tmp[0][t] = v;
    __syncthreads();
    for (int off = 1; off < 1024; off <<= 1) {
        int nv = tmp[buf][t] + ((t >= off) ? tmp[buf][t - off] : 0);
        buf ^= 1; tmp[buf][t] = nv;
        __syncthreads();
    }
    int incl = tmp[buf][t];
    if (idx < total) tab[idx] = incl - v;
    if (t == 1023) bs[blockIdx.x] = incl;
}

__global__ void k_scan2(int* __restrict__ bsum, int NB) {
    __shared__ int tmp[2][256];
    __shared__ int carry_s;
    int t = threadIdx.x;
    if (t == 0) carry_s = 0;
    __syncthreads();
    for (int chunk = 0; chunk < NB; chunk += 256) {
        int idx = chunk + t;
        int v = (idx < NB) ? bsum[idx] : 0;
        int buf = 0;
        tmp[0][t] = v;
        __syncthreads();
        for (int off = 1; off < 256; off <<= 1) {
            int nv = tmp[buf][t] + ((t >= off) ? tmp[buf][t - off] : 0);
            buf ^= 1; tmp[buf][t] = nv;
            __syncthreads();
        }
        int incl = tmp[buf][t];
        int carry = carry_s;
        if (idx < NB) bsum[idx] = carry + incl - v;
        __syncthreads();
        if (t == 255) carry_s = carry + incl;
        __syncthreads();
    }
}

__global__ void k_scanB3(int* __restrict__ tab, int total, const int* __restrict__ bs,
                         int* __restrict__ segBase, int NBKT, int E) {
    const int idx = blockIdx.x * 1024 + threadIdx.x;
    if (idx < total) {
        int v = tab[idx] + bs[blockIdx.x];
        tab[idx] = v;
        if ((idx & (P - 1)) == 0) segBase[idx / P] = v;
    }
    if (idx == 0) segBase[NBKT] = E;
}

// ---------------------------------------------- reduce row partials -> dis
__global__ void k_disr(const unsigned int* __restrict__ partialR, int W, int N,
                       float* __restrict__ dis) {
    const int w = blockIdx.x * blockDim.x + threadIdx.x;
    if (w >= W) return;
    const unsigned int* pr = partialR + w;
    unsigned int accA = 0, accB = 0;            // byte lanes, totals <= ~66
    for (int p = 0; p < P; p++) {
        unsigned int v = pr[(size_t)p * W];
        accA += v & 0x0F0F0F0Fu;
        accB += (v >> 4) & 0x0F0F0F0Fu;
    }
    int d[8];
    d[0] = accA & 255; d[2] = (accA >> 8) & 255;
    d[4] = (accA >> 16) & 255; d[6] = accA >> 24;
    d[1] = accB & 255; d[3] = (accB >> 8) & 255;
    d[5] = (accB >> 16) & 255; d[7] = accB >> 24;
    const int n0 = w * 8;
#pragma unroll
    for (int k = 0; k < 8; k++)
        if (n0 + k < N) dis[n0 + k] = d[k] ? rsqrtf((float)d[k]) : 0.f;
}

// ------------------------------- stage into bucket-major runs (16B records)
__global__ __launch_bounds__(TPBW)
void k_stage(const int* __restrict__ ei, const float2* __restrict__ ea,
             const float* __restrict__ dis, int E, int sliceLen,
             const int* __restrict__ cntTab, int NBKT, int4* __restrict__ staged) {
    __shared__ int lb[MAXB], lbase[MAXB];
    const int p = blockIdx.x;
    for (int t = threadIdx.x; t < NBKT; t += TPBW) {
        lb[t] = 0;
        lbase[t] = cntTab[t * P + p];
    }
    __syncthreads();
    const int* colA = ei + E;
    const int s = p * sliceLen, send = min(s + sliceLen, E);
    for (int e = s + threadIdx.x; e < send; e += TPBW) {
        int c = colA[e], r = ei[e];
        int b = c >> BSH;
        float nrm = dis[r] * dis[c];
        int pos = lbase[b] + atomicAdd(&lb[b], 1);
        float2 ev = ea[e];
        staged[pos] = make_int4((r << BSH) | (c & (BKN - 1)), __float_as_int(nrm),
                                __float_as_int(nrm * ev.x), __float_as_int(nrm * ev.y));
    }
}

// --------- per-bucket counting sort (LDS-buffered, sequential writeout)
// single staged read; rank kept in registers; also accumulates ea-sums.
__global__ __launch_bounds__(TPBW)
void k_sort(const int4* __restrict__ staged, const int* __restrict__ segBase,
            int N, int2* __restrict__ rec, int* __restrict__ base,
            int* __restrict__ cnt, float2* __restrict__ eaS) {
    __shared__ int2 sbuf[SBUF];
    __shared__ int lfill[BKN], lexc[BKN];
    __shared__ float lacx[BKN], lacy[BKN];
    __shared__ int tmp[2][BKN];
    const int b = blockIdx.x, t = threadIdx.x;
    const int s0 = segBase[b], s1 = segBase[b + 1], c0 = b << BSH;
    if (t < BKN) { lfill[t] = 0; lacx[t] = 0.f; lacy[t] = 0.f; }
    __syncthreads();
    int4 rv[ITER]; int rk[ITER]; int nIt = 0;
    for (int e = s0 + t; e < s1; e += TPBW) {
        if (nIt < ITER) {
            int4 v = staged[e];
            rv[nIt] = v;
            rk[nIt] = atomicAdd(&lfill[v.x & (BKN - 1)], 1);
            nIt++;
        }
    }
    __syncthreads();
    int buf = 0;
    if (t < BKN) tmp[0][t] = lfill[t];
    __syncthreads();
    for (int off = 1; off < BKN; off <<= 1) {
        if (t < BKN) {
            int nv = tmp[buf][t] + ((t >= off) ? tmp[buf][t - off] : 0);
            tmp[buf ^ 1][t] = nv;
        }
        __syncthreads();
        buf ^= 1;
    }
    if (t < BKN) {
        int incl = tmp[buf][t];
        int cj = lfill[t];
        lexc[t] = incl - cj;
        int node = c0 + t;
        if (node < N) { base[node] = s0 + incl - cj; cnt[node] = cj; }
    }
    __syncthreads();
    for (int k = 0; k < nIt; k++) {
        int4 v = rv[k];
        int j = v.x & (BKN - 1);
        int r = ((unsigned)v.x) >> BSH;
        int pos = lexc[j] + rk[k];
        int2 o = make_int2(r, v.y);
        if (pos < SBUF) sbuf[pos] = o;
        else rec[s0 + pos] = o;                    // impossible-case fallback
        unsafeAtomicAdd(&lacx[j], __int_as_float(v.z));
        unsafeAtomicAdd(&lacy[j], __int_as_float(v.w));
    }
    __syncthreads();
    const int len = s1 - s0;
    for (int k = t; k < len && k < SBUF; k += TPBW) rec[s0 + k] = sbuf[k];
    if (t < BKN && c0 + t < N) eaS[c0 + t] = make_float2(lacx[t], lacy[t]);
}

// ---------------- layer-1: CSR walk for x-sums + node update
__global__ void k_node1(const float* __restrict__ x, const int2* __restrict__ rec,
                        const int* __restrict__ base, const int* __restrict__ cnt,
                        const float2* __restrict__ eaS,
                        const float* __restrict__ Wc, const float* __restrict__ bc,
                        const float* __restrict__ Wn,
                        float* __restrict__ h, int N) {
    __shared__ float sWc[3 * 16], sbc[16], sWn[5 * 16];
    for (int t = threadIdx.x; t < 48; t += blockDim.x) sWc[t] = Wc[t];
    for (int t = threadIdx.x; t < 16; t += blockDim.x) sbc[t] = bc[t];
    for (int t = threadIdx.x; t < 80; t += blockDim.x) sWn[t] = Wn[t];
    __syncthreads();
    int i = blockIdx.x * blockDim.x + threadIdx.x;
    if (i >= N) return;
    int b0 = base[i], dg = cnt[i];
    float a0 = 0, a1 = 0, a2 = 0;
    for (int k = 0; k < dg; k++) {
        int2 rv = rec[b0 + k];
        float nrm = __int_as_float(rv.y);
        const float* xr = x + 3 * (long)rv.x;
        a0 += nrm * xr[0];
        a1 += nrm * xr[1];
        a2 += nrm * xr[2];
    }
    float inv = 1.0f / fmaxf((float)dg, 1.0f);
    float2 es = eaS[i];
    float m[5] = {a0 * inv, a1 * inv, a2 * inv, es.x * inv, es.y * inv};
    float xv[3];
#pragma unroll
    for (int j = 0; j < 3; j++) xv[j] = x[3 * (long)i + j];
    float o[16];
#pragma unroll
    for (int k = 0; k < 16; k++) {
        float v = sbc[k];
#pragma unroll
        for (int j = 0; j < 3; j++) v += xv[j] * sWc[j * 16 + k];
#pragma unroll
        for (int j = 0; j < 5; j++) v += m[j] * sWn[j * 16 + k];
        o[k] = fmaxf(v, 0.0f);
    }
    float4* hp = (float4*)(h + 16 * (long)i);
#pragma unroll
    for (int q = 0; q < 4; q++)
        hp[q] = make_float4(o[4 * q], o[4 * q + 1], o[4 * q + 2], o[4 * q + 3]);
}

// ---- layer-2: 8 threads/node CSR walk + shfl reduce + node update + pooling
__global__ __launch_bounds__(TPBW)
void k_g2(const int2* __restrict__ rec, const int* __restrict__ base,
          const int* __restrict__ cnt, const float2* __restrict__ eaS,
          const float* __restrict__ h, const int* __restrict__ batch, int N,
          const float* __restrict__ Wc, const float* __restrict__ bc,
          const float* __restrict__ Wn,
          float* __restrict__ pool, int* __restrict__ poolcnt) {
    __shared__ float smr[BKN][17];
    __shared__ float sWc[256], sbc[16], sWn[288], sp[1024];
    __shared__ int sc[64];
    const int b = blockIdx.x, t = threadIdx.x;
    const int c0 = b << BSH;
    for (int k = t; k < 256; k += TPBW) sWc[k] = Wc[k];
    for (int k = t; k < 16;  k += TPBW) sbc[k] = bc[k];
    for (int k = t; k < 288; k += TPBW) sWn[k] = Wn[k];
    for (int k = t; k < 1024; k += TPBW) sp[k] = 0.f;
    if (t < 64) sc[t] = 0;
    __syncthreads();
    const int grp = t >> 3, sub = t & 7;
    const int node = c0 + grp;
    float mm[16];
#pragma unroll
    for (int k = 0; k < 16; k++) mm[k] = 0.f;
    if (node < N) {
        int b0 = base[node], dg = cnt[node];
        for (int e = sub; e < dg; e += 8) {
            int2 rv = rec[b0 + e];
            float nrm = __int_as_float(rv.y);
            const float4* hr = (const float4*)(h + 16 * (long)rv.x);
            float4 h0 = hr[0], h1 = hr[1], h2 = hr[2], h3 = hr[3];
            mm[0]  += nrm * h0.x;  mm[1]  += nrm * h0.y;
            mm[2]  += nrm * h0.z;  mm[3]  += nrm * h0.w;
            mm[4]  += nrm * h1.x;  mm[5]  += nrm * h1.y;
            mm[6]  += nrm * h1.z;  mm[7]  += nrm * h1.w;
            mm[8]  += nrm * h2.x;  mm[9]  += nrm * h2.y;
            mm[10] += nrm * h2.z;  mm[11] += nrm * h2.w;
            mm[12] += nrm * h3.x;  mm[13] += nrm * h3.y;
            mm[14] += nrm * h3.z;  mm[15] += nrm * h3.w;
        }
    }
#pragma unroll
    for (int k = 0; k < 16; k++) {
        mm[k] += __shfl_down(mm[k], 4, 8);
        mm[k] += __shfl_down(mm[k], 2, 8);
        mm[k] += __shfl_down(mm[k], 1, 8);
    }
    if (sub == 0) {
#pragma unroll
        for (int k = 0; k < 16; k++) smr[grp][k] = mm[k];
    }
    __syncthreads();
    if (t < BKN) {
        int nd = c0 + t;
        if (nd < N) {
            float inv = 1.0f / fmaxf((float)cnt[nd], 1.0f);
            float m[18];
#pragma unroll
            for (int k = 0; k < 16; k++) m[k] = smr[t][k] * inv;
            float2 es = eaS[nd];
            m[16] = es.x * inv; m[17] = es.y * inv;
            float hv[16];
            const float4* hp = (const float4*)(h + 16 * (long)nd);
#pragma unroll
            for (int q = 0; q < 4; q++) {
                float4 t4 = hp[q];
                hv[4 * q] = t4.x; hv[4 * q + 1] = t4.y;
                hv[4 * q + 2] = t4.z; hv[4 * q + 3] = t4.w;
            }
            int g = batch[nd];
            atomicAdd(&sc[g], 1);
#pragma unroll
            for (int k = 0; k < 16; k++) {
                float v = sbc[k];
#pragma unroll
                for (int j = 0; j < 16; j++) v += hv[j] * sWc[j * 16 + k];
#pragma unroll
                for (int j = 0; j < 18; j++) v += m[j] * sWn[j * 16 + k];
                v = fmaxf(v, 0.0f);
                unsafeAtomicAdd(&sp[g * 16 + k], v);
            }
        }
    }
    __syncthreads();
    for (int k = t; k < 1024; k += TPBW)
        if (sp[k] != 0.0f) unsafeAtomicAdd(&pool[k], sp[k]);
    if (t < 64 && sc[t]) atomicAdd(&poolcnt[t], sc[t]);
}

// ---------------------------------------------------------------- MLP head
__global__ void k_final(const float* __restrict__ pool, const int* __restrict__ poolcnt,
                        const float* __restrict__ Wl1, const float* __restrict__ bl1,
                        const float* __restrict__ Wl2, const float* __restrict__ bl2,
                        float* __restrict__ out) {
    int g = threadIdx.x;
    if (g >= 64) return;
    float inv = 1.0f / fmaxf((float)poolcnt[g], 1.0f);
    float gv[16];
#pragma unroll
    for (int k = 0; k < 16; k++) gv[k] = pool[g * 16 + k] * inv;
    float t[16];
#pragma unroll
    for (int k = 0; k < 16; k++) {
        float v = bl1[k];
#pragma unroll
        for (int j = 0; j < 16; j++) v += gv[j] * Wl1[j * 16 + k];
        t[k] = fmaxf(v, 0.0f);
    }
    float o0 = bl2[0], o1 = bl2[1];
#pragma unroll
    for (int j = 0; j < 16; j++) {
        o0 += t[j] * Wl2[j * 2 + 0];
        o1 += t[j] * Wl2[j * 2 + 1];
    }
    out[2 * g + 0] = o0;
    out[2 * g + 1] = o1;
}

extern "C" void kernel_launch(void* const* d_in, const int* in_sizes, int n_in,
                              void* d_out, int out_size, void* d_ws, size_t ws_size,
                              hipStream_t stream) {
    const float* x     = (const float*)d_in[0];
    const int*   ei    = (const int*)  d_in[1];
    const float* ea    = (const float*)d_in[2];
    const int*   batch = (const int*)  d_in[3];
    const float* Wc1   = (const float*)d_in[4];
    const float* bc1   = (const float*)d_in[5];
    const float* Wn1   = (const float*)d_in[6];
    const float* Wc2   = (const float*)d_in[7];
    const float* bc2   = (const float*)d_in[8];
    const float* Wn2   = (const float*)d_in[9];
    const float* Wl1   = (const float*)d_in[10];
    const float* bl1   = (const float*)d_in[11];
    const float* Wl2   = (const float*)d_in[12];
    const float* bl2   = (const float*)d_in[13];
    float* out = (float*)d_out;

    const int N  = in_sizes[0] / 3;
    const int E  = in_sizes[1] / 2;
    const int NBKT = (N + BKN - 1) >> BSH;        // <= 800 for N <= 102400
    const int W  = (N + 7) >> 3;                  // <= 12800
    const int total = NBKT * P;
    const int NSB = (total + 1023) / 1024;
    const int sliceLen = (E + P - 1) / P;

    char* ws = (char*)d_ws;
    size_t o = 0;
    auto alloc = [&](size_t bytes) {
        void* p = ws + o;
        o += (bytes + 255) & ~(size_t)255;
        return p;
    };
    // zeroed region (pool + poolcnt only)
    float* pool    = (float*)alloc(64 * 16 * 4);
    int*   poolcnt = (int*)  alloc(64 * 4);
    size_t zbytes = o;
    // non-zeroed
    float*  dis     = (float*)alloc((size_t)N * 4);
    int*    cnt     = (int*)  alloc((size_t)N * 4);
    int*    base    = (int*)  alloc((size_t)N * 4);
    float2* eaS     = (float2*)alloc((size_t)N * 8);
    int*    cntTab  = (int*)  alloc((size_t)total * 4);
    int*    bs      = (int*)  alloc((size_t)NSB * 4);
    int*    segBase = (int*)  alloc((size_t)(NBKT + 1) * 4);
    // region B: partialR [prep2..disr], then rec [sort..g2]
    size_t szPR = (size_t)P * W * 4, szRC = (size_t)E * 8;
    char* regionB = (char*)alloc(szPR > szRC ? szPR : szRC);
    unsigned int* partialR = (unsigned int*)regionB;
    int2* rec = (int2*)regionB;
    // region A: staged [stage..sort], then h [node1..g2]
    size_t szST = (size_t)E * 16, szH = (size_t)N * 16 * 4;
    char* regionA = (char*)alloc(szST > szH ? szST : szH);
    int4*  staged = (int4*)regionA;
    float* h      = (float*)regionA;
    (void)ws_size;

    hipMemsetAsync(d_ws, 0, zbytes, stream);

    const int gN = (N + TPB - 1) / TPB;
    k_prep2 <<<P, TPBW, 0, stream>>>(ei, E, sliceLen, W, NBKT, partialR, cntTab);
    k_scanB1<<<NSB, 1024, 0, stream>>>(cntTab, total, bs);
    k_scan2 <<<1, 256, 0, stream>>>(bs, NSB);
    k_scanB3<<<NSB, 1024, 0, stream>>>(cntTab, total, bs, segBase, NBKT, E);
    k_disr  <<<(W + TPB - 1) / TPB, TPB, 0, stream>>>(partialR, W, N, dis);
    k_stage <<<P, TPBW, 0, stream>>>(ei, (const float2*)ea, dis, E, sliceLen,
                                     cntTab, NBKT, staged);
    k_sort  <<<NBKT, TPBW, 0, stream>>>(staged, segBase, N, rec, base, cnt, eaS);
    k_node1 <<<gN, TPB, 0, stream>>>(x, rec, base, cnt, eaS, Wc1, bc1, Wn1, h, N);
    k_g2    <<<NBKT, TPBW, 0, stream>>>(rec, base, cnt, eaS, h, batch, N,
                                        Wc2, bc2, Wn2, pool, poolcnt);
    k_final <<<1, 64, 0, stream>>>(pool, poolcnt, Wl1, bl1, Wl2, bl2, out);
}